// Round 1
// baseline (290.506 us; speedup 1.0000x reference)
//
#include <hip/hip_runtime.h>

#define NN_F 128
#define NH1 100
#define NH2 16
#define ND2 25
#define NFEAT 41   // NH2 + ND2

// ---------------- degree / dis ----------------
__global__ void k_count(const int* __restrict__ ei, int* __restrict__ cnt, int E) {
    int i = blockIdx.x * blockDim.x + threadIdx.x;
    if (i < E) atomicAdd(&cnt[ei[E + i]], 1);
}

__global__ void k_dis(const int* __restrict__ cnt, float* __restrict__ dis, int n) {
    int i = blockIdx.x * blockDim.x + threadIdx.x;
    if (i < n) dis[i] = rsqrtf((float)cnt[i] + 1.0f);  // +1 self-loop; always > 0
}

// ---------------- exclusive scan (3 kernels, counts -> offsets) ----------------
__global__ void k_scan1(const int* __restrict__ cnt, int* __restrict__ excl,
                        int* __restrict__ partials, int n) {
    __shared__ int tmp[256];
    int i = blockIdx.x * 256 + threadIdx.x;
    int v = (i < n) ? cnt[i] : 0;
    tmp[threadIdx.x] = v;
    __syncthreads();
    for (int d = 1; d < 256; d <<= 1) {
        int t = (threadIdx.x >= d) ? tmp[threadIdx.x - d] : 0;
        __syncthreads();
        tmp[threadIdx.x] += t;
        __syncthreads();
    }
    if (i < n) excl[i] = tmp[threadIdx.x] - v;
    if (threadIdx.x == 255) partials[blockIdx.x] = tmp[255];
}

__global__ void k_scan2(int* partials, int nb) {
    __shared__ int tmp[256];
    int v = (threadIdx.x < nb) ? partials[threadIdx.x] : 0;
    tmp[threadIdx.x] = v;
    __syncthreads();
    for (int d = 1; d < 256; d <<= 1) {
        int t = (threadIdx.x >= d) ? tmp[threadIdx.x - d] : 0;
        __syncthreads();
        tmp[threadIdx.x] += t;
        __syncthreads();
    }
    if (threadIdx.x < nb) partials[threadIdx.x] = tmp[threadIdx.x] - v;  // exclusive
}

__global__ void k_scan3(int* __restrict__ off, const int* __restrict__ partials, int n, int E) {
    int i = blockIdx.x * 256 + threadIdx.x;
    if (i < n) off[i] += partials[blockIdx.x];
    if (i == 0) off[n] = E;
}

// ---------------- CSR fill ----------------
__global__ void k_fill(const int* __restrict__ ei, const int* __restrict__ off,
                       int* __restrict__ cur, const float* __restrict__ dis,
                       int* __restrict__ csrc, float* __restrict__ cnorm, int E) {
    int i = blockIdx.x * blockDim.x + threadIdx.x;
    if (i >= E) return;
    int s = ei[i], d = ei[E + i];
    int p = atomicAdd(&cur[d], 1);
    int slot = off[d] + p;
    csrc[slot] = s;
    cnorm[slot] = dis[s] * dis[d];
}

// ---------------- GEMM1: hx = x @ W1  (N x 128 @ 128 x 100) ----------------
__global__ __launch_bounds__(256) void k_gemm1(const float* __restrict__ x,
                                               const float* __restrict__ W1,
                                               float* __restrict__ hx, int nrp) {
    __shared__ float w[NN_F * NH1];  // 51.2 KB
    for (int i = threadIdx.x; i < NN_F * NH1; i += 256) w[i] = W1[i];
    __syncthreads();
    int idx = blockIdx.x * 256 + threadIdx.x;
    if (idx >= nrp * 25) return;
    int rp = idx / 25, cg = idx % 25;
    const float* x0 = x + (rp * 2) * NN_F;
    const float* x1 = x0 + NN_F;
    float4 a0 = {0, 0, 0, 0}, a1 = {0, 0, 0, 0};
#pragma unroll 8
    for (int k = 0; k < NN_F; ++k) {
        float4 wv = *(const float4*)&w[k * NH1 + cg * 4];
        float xv0 = x0[k], xv1 = x1[k];
        a0.x = fmaf(xv0, wv.x, a0.x); a0.y = fmaf(xv0, wv.y, a0.y);
        a0.z = fmaf(xv0, wv.z, a0.z); a0.w = fmaf(xv0, wv.w, a0.w);
        a1.x = fmaf(xv1, wv.x, a1.x); a1.y = fmaf(xv1, wv.y, a1.y);
        a1.z = fmaf(xv1, wv.z, a1.z); a1.w = fmaf(xv1, wv.w, a1.w);
    }
    *(float4*)&hx[(rp * 2) * NH1 + cg * 4] = a0;
    *(float4*)&hx[(rp * 2 + 1) * NH1 + cg * 4] = a1;
}

// ---------------- Agg layer1: wave per node, fused self-loop+bias+relu -------
__global__ __launch_bounds__(256) void k_agg1(const float* __restrict__ hx,
                                              const int* __restrict__ off,
                                              const int* __restrict__ csrc,
                                              const float* __restrict__ cnorm,
                                              const float* __restrict__ dis,
                                              const float* __restrict__ b1,
                                              float* __restrict__ h, int n) {
    int wid = (blockIdx.x * 256 + threadIdx.x) >> 6;
    int lane = threadIdx.x & 63;
    if (wid >= n) return;
    float dn = dis[wid];
    float sn = dn * dn;
    int f1 = lane + 64;
    bool has1 = f1 < NH1;
    const float* hr = hx + wid * NH1;
    float acc0 = hr[lane] * sn;
    float acc1 = has1 ? hr[f1] * sn : 0.f;
    int jb = off[wid], je = off[wid + 1];
    for (int j = jb; j < je; ++j) {
        int s = csrc[j];
        float nm = cnorm[j];
        const float* hs = hx + s * NH1;
        acc0 += hs[lane] * nm;
        if (has1) acc1 += hs[f1] * nm;
    }
    h[wid * NH1 + lane] = fmaxf(acc0 + b1[lane], 0.f);
    if (has1) h[wid * NH1 + f1] = fmaxf(acc1 + b1[f1], 0.f);
}

// ---------------- GEMM2: h2 = h @ W2 (N x 100 @ 100 x 16) ----------------
__global__ __launch_bounds__(256) void k_gemm2(const float* __restrict__ h,
                                               const float* __restrict__ W2,
                                               float* __restrict__ h2, int n) {
    __shared__ float wt[NH2 * NH1];  // transposed [col][k]
    for (int i = threadIdx.x; i < NH1 * NH2; i += 256) {
        int k = i / NH2, c = i % NH2;
        wt[c * NH1 + k] = W2[i];
    }
    __syncthreads();
    int idx = blockIdx.x * 256 + threadIdx.x;
    if (idx >= n * NH2) return;
    int row = idx >> 4, col = idx & 15;
    const float* hr = h + row * NH1;
    const float* wr = wt + col * NH1;
    float acc = 0.f;
#pragma unroll
    for (int k = 0; k < NH1; k += 4) {
        float4 hv = *(const float4*)&hr[k];
        float4 wv = *(const float4*)&wr[k];
        acc = fmaf(hv.x, wv.x, acc);
        acc = fmaf(hv.y, wv.y, acc);
        acc = fmaf(hv.z, wv.z, acc);
        acc = fmaf(hv.w, wv.w, acc);
    }
    h2[idx] = acc;
}

// ------- Agg layer2 + bias + relu + row-normalize (thread per node-feat) -----
__global__ __launch_bounds__(256) void k_agg2(const float* __restrict__ h2,
                                              const int* __restrict__ off,
                                              const int* __restrict__ csrc,
                                              const float* __restrict__ cnorm,
                                              const float* __restrict__ dis,
                                              const float* __restrict__ b2,
                                              float* __restrict__ emb, int n) {
    int idx = blockIdx.x * 256 + threadIdx.x;
    if (idx >= n * NH2) return;
    int node = idx >> 4, f = idx & 15;
    float dn = dis[node];
    float acc = h2[idx] * dn * dn;
    int jb = off[node], je = off[node + 1];
    for (int j = jb; j < je; ++j)
        acc += h2[(csrc[j] << 4) + f] * cnorm[j];
    float v = fmaxf(acc + b2[f], 0.f);
    float ss = v * v;
    ss += __shfl_xor(ss, 1);
    ss += __shfl_xor(ss, 2);
    ss += __shfl_xor(ss, 4);
    ss += __shfl_xor(ss, 8);
    float nrm = sqrtf(ss);
    float scale = nrm > 1.f ? 1.f / (nrm + 1e-7f) : 1.f;
    emb[idx] = v * scale;
}

// ---------------- Decoder: thread per edge ----------------
__global__ __launch_bounds__(256) void k_dec(const float* __restrict__ emb,
                                             const int* __restrict__ te,
                                             const float* __restrict__ PI,
                                             const float* __restrict__ ey,
                                             const float* __restrict__ Wl1,
                                             const float* __restrict__ bl1,
                                             const float* __restrict__ Wl,
                                             const float* __restrict__ bl,
                                             float* __restrict__ out, int ne) {
    int e = blockIdx.x * 256 + threadIdx.x;
    if (e >= ne) return;
    int a = te[2 * e], b = te[2 * e + 1];
    float feat[NFEAT];
    const float4* ea = (const float4*)(emb + a * NH2);
    const float4* eb = (const float4*)(emb + b * NH2);
#pragma unroll
    for (int q = 0; q < 4; ++q) {
        float4 va = ea[q], vb = eb[q];
        float dx = va.x - vb.x, dy = va.y - vb.y, dz = va.z - vb.z, dw = va.w - vb.w;
        feat[q * 4 + 0] = dx * dx; feat[q * 4 + 1] = dy * dy;
        feat[q * 4 + 2] = dz * dz; feat[q * 4 + 3] = dw * dw;
    }
    const float* pi = PI + e * ND2;
#pragma unroll
    for (int q = 0; q < ND2; ++q) feat[NH2 + q] = pi[q];
    float s = 0.f;
    for (int j = 0; j < ND2; ++j) {
        float acc = bl1[j];
#pragma unroll
        for (int k = 0; k < NFEAT; ++k) acc = fmaf(feat[k], Wl1[k * ND2 + j], acc);
        acc = acc > 0.f ? acc : 0.2f * acc;  // leaky_relu slope 0.2
        s = fmaf(acc, Wl[j], s);
    }
    s += bl[0];
    s = fabsf(s);
    s = fminf(s, 40.0f);
    out[e] = 1.0f / (expf(s - 2.0f) + 1.0f);
    out[ne + e] = ey[e];
}

static inline int cdiv(int a, int b) { return (a + b - 1) / b; }

extern "C" void kernel_launch(void* const* d_in, const int* in_sizes, int n_in,
                              void* d_out, int out_size, void* d_ws, size_t ws_size,
                              hipStream_t stream) {
    const float* x   = (const float*)d_in[0];
    const int*   ei  = (const int*)d_in[1];
    const int*   te  = (const int*)d_in[2];
    const float* PI  = (const float*)d_in[3];
    const float* ey  = (const float*)d_in[4];
    const float* W1  = (const float*)d_in[5];
    const float* b1  = (const float*)d_in[6];
    const float* W2  = (const float*)d_in[7];
    const float* b2  = (const float*)d_in[8];
    const float* Wl1 = (const float*)d_in[9];
    const float* bl1 = (const float*)d_in[10];
    const float* Wl  = (const float*)d_in[11];
    const float* bl  = (const float*)d_in[12];
    float* out = (float*)d_out;

    const int n  = in_sizes[0] / NN_F;   // 50000
    const int E  = in_sizes[1] / 2;      // 800000
    const int ne = in_sizes[4];          // 200000

    // workspace carve-up
    char* ws = (char*)d_ws;
    size_t o = 0;
    auto carve = [&](size_t bytes) -> void* {
        void* p = ws + o;
        o = (o + bytes + 255) & ~(size_t)255;
        return p;
    };
    int*   cnt      = (int*)carve((size_t)n * 4);
    float* dis      = (float*)carve((size_t)n * 4);
    int*   off      = (int*)carve((size_t)(n + 1) * 4);
    int*   cur      = (int*)carve((size_t)n * 4);
    int*   partials = (int*)carve(256 * 4);
    int*   csrc     = (int*)carve((size_t)E * 4);
    float* cnorm    = (float*)carve((size_t)E * 4);
    float* hx       = (float*)carve((size_t)n * NH1 * 4);
    float* h        = (float*)carve((size_t)n * NH1 * 4);
    float* h2       = (float*)carve((size_t)n * NH2 * 4);
    float* emb      = (float*)carve((size_t)n * NH2 * 4);

    const int NB = cdiv(n, 256);  // 196

    hipMemsetAsync(cnt, 0, (size_t)n * 4, stream);
    hipMemsetAsync(cur, 0, (size_t)n * 4, stream);

    k_count<<<cdiv(E, 256), 256, 0, stream>>>(ei, cnt, E);
    k_dis<<<NB, 256, 0, stream>>>(cnt, dis, n);
    k_scan1<<<NB, 256, 0, stream>>>(cnt, off, partials, n);
    k_scan2<<<1, 256, 0, stream>>>(partials, NB);
    k_scan3<<<NB, 256, 0, stream>>>(off, partials, n, E);
    k_fill<<<cdiv(E, 256), 256, 0, stream>>>(ei, off, cur, dis, csrc, cnorm, E);

    k_gemm1<<<cdiv((n / 2) * 25, 256), 256, 0, stream>>>(x, W1, hx, n / 2);
    k_agg1<<<cdiv(n * 64, 256), 256, 0, stream>>>(hx, off, csrc, cnorm, dis, b1, h, n);
    k_gemm2<<<cdiv(n * NH2, 256), 256, 0, stream>>>(h, W2, h2, n);
    k_agg2<<<cdiv(n * NH2, 256), 256, 0, stream>>>(h2, off, csrc, cnorm, dis, b2, emb, n);
    k_dec<<<cdiv(ne, 256), 256, 0, stream>>>(emb, te, PI, ey, Wl1, bl1, Wl, bl, out, ne);
}

// Round 2
// 238.770 us; speedup vs baseline: 1.2167x; 1.2167x over previous
//
#include <hip/hip_runtime.h>
#include <hip/hip_fp16.h>

#define NN_F 128
#define NH1 100
#define NH2 16
#define ND2 25
#define NFEAT 41   // NH2 + ND2

// ---------------- degree / dis ----------------
__global__ void k_count(const int* __restrict__ ei, int* __restrict__ cnt, int E) {
    int i = blockIdx.x * blockDim.x + threadIdx.x;
    if (i < E) atomicAdd(&cnt[ei[E + i]], 1);
}

__global__ void k_dis(const int* __restrict__ cnt, float* __restrict__ dis, int n) {
    int i = blockIdx.x * blockDim.x + threadIdx.x;
    if (i < n) dis[i] = rsqrtf((float)cnt[i] + 1.0f);  // +1 self-loop; always > 0
}

// ---------------- exclusive scan (3 kernels, counts -> offsets) ----------------
__global__ void k_scan1(const int* __restrict__ cnt, int* __restrict__ excl,
                        int* __restrict__ partials, int n) {
    __shared__ int tmp[256];
    int i = blockIdx.x * 256 + threadIdx.x;
    int v = (i < n) ? cnt[i] : 0;
    tmp[threadIdx.x] = v;
    __syncthreads();
    for (int d = 1; d < 256; d <<= 1) {
        int t = (threadIdx.x >= d) ? tmp[threadIdx.x - d] : 0;
        __syncthreads();
        tmp[threadIdx.x] += t;
        __syncthreads();
    }
    if (i < n) excl[i] = tmp[threadIdx.x] - v;
    if (threadIdx.x == 255) partials[blockIdx.x] = tmp[255];
}

__global__ void k_scan2(int* partials, int nb) {
    __shared__ int tmp[256];
    int v = (threadIdx.x < nb) ? partials[threadIdx.x] : 0;
    tmp[threadIdx.x] = v;
    __syncthreads();
    for (int d = 1; d < 256; d <<= 1) {
        int t = (threadIdx.x >= d) ? tmp[threadIdx.x - d] : 0;
        __syncthreads();
        tmp[threadIdx.x] += t;
        __syncthreads();
    }
    if (threadIdx.x < nb) partials[threadIdx.x] = tmp[threadIdx.x] - v;  // exclusive
}

__global__ void k_scan3(int* __restrict__ off, const int* __restrict__ partials, int n, int E) {
    int i = blockIdx.x * 256 + threadIdx.x;
    if (i < n) off[i] += partials[blockIdx.x];
    if (i == 0) off[n] = E;
}

// ---------------- CSR fill ----------------
__global__ void k_fill(const int* __restrict__ ei, const int* __restrict__ off,
                       int* __restrict__ cur, const float* __restrict__ dis,
                       int* __restrict__ csrc, float* __restrict__ cnorm, int E) {
    int i = blockIdx.x * blockDim.x + threadIdx.x;
    if (i >= E) return;
    int s = ei[i], d = ei[E + i];
    int p = atomicAdd(&cur[d], 1);
    int slot = off[d] + p;
    csrc[slot] = s;
    cnorm[slot] = dis[s] * dis[d];
}

// ---------------- GEMM1: hx = x @ W1  (N x 128 @ 128 x 100), fp16 out -------
struct h4pack { __half2 a, b; };

__global__ __launch_bounds__(256) void k_gemm1(const float* __restrict__ x,
                                               const float* __restrict__ W1,
                                               __half* __restrict__ hx, int nrp) {
    __shared__ float w[NN_F * NH1];  // 51.2 KB
    for (int i = threadIdx.x; i < NN_F * NH1; i += 256) w[i] = W1[i];
    __syncthreads();
    int idx = blockIdx.x * 256 + threadIdx.x;
    if (idx >= nrp * 25) return;
    int rp = idx / 25, cg = idx % 25;
    const float* x0 = x + (size_t)(rp * 2) * NN_F;
    const float* x1 = x0 + NN_F;
    float4 a0 = {0, 0, 0, 0}, a1 = {0, 0, 0, 0};
#pragma unroll 8
    for (int k = 0; k < NN_F; ++k) {
        float4 wv = *(const float4*)&w[k * NH1 + cg * 4];
        float xv0 = x0[k], xv1 = x1[k];
        a0.x = fmaf(xv0, wv.x, a0.x); a0.y = fmaf(xv0, wv.y, a0.y);
        a0.z = fmaf(xv0, wv.z, a0.z); a0.w = fmaf(xv0, wv.w, a0.w);
        a1.x = fmaf(xv1, wv.x, a1.x); a1.y = fmaf(xv1, wv.y, a1.y);
        a1.z = fmaf(xv1, wv.z, a1.z); a1.w = fmaf(xv1, wv.w, a1.w);
    }
    h4pack p0 = { __floats2half2_rn(a0.x, a0.y), __floats2half2_rn(a0.z, a0.w) };
    h4pack p1 = { __floats2half2_rn(a1.x, a1.y), __floats2half2_rn(a1.z, a1.w) };
    *(h4pack*)&hx[(size_t)(rp * 2) * NH1 + cg * 4] = p0;
    *(h4pack*)&hx[(size_t)(rp * 2 + 1) * NH1 + cg * 4] = p1;
}

// ------ Agg layer1: wave/node, 50 lanes x half2, unroll 2, bias+relu --------
__global__ __launch_bounds__(256) void k_agg1(const __half* __restrict__ hx,
                                              const int* __restrict__ off,
                                              const int* __restrict__ csrc,
                                              const float* __restrict__ cnorm,
                                              const float* __restrict__ dis,
                                              const float* __restrict__ b1,
                                              float* __restrict__ h, int n) {
    int wid = (blockIdx.x * 256 + threadIdx.x) >> 6;
    int lane = threadIdx.x & 63;
    if (wid >= n) return;
    bool act = lane < 50;
    float dn = dis[wid];
    float sn = dn * dn;
    float ax = 0.f, ay = 0.f;
    if (act) {
        float2 v = __half22float2(((const __half2*)(hx + (size_t)wid * NH1))[lane]);
        ax = v.x * sn; ay = v.y * sn;
    }
    int jb = off[wid], je = off[wid + 1];
    int j = jb;
    for (; j + 2 <= je; j += 2) {
        int s0 = csrc[j], s1 = csrc[j + 1];
        float n0 = cnorm[j], n1 = cnorm[j + 1];
        __half2 g0 = __half2(), g1 = __half2();
        if (act) {
            g0 = ((const __half2*)(hx + (size_t)s0 * NH1))[lane];
            g1 = ((const __half2*)(hx + (size_t)s1 * NH1))[lane];
        }
        float2 v0 = __half22float2(g0), v1 = __half22float2(g1);
        ax = fmaf(v0.x, n0, ax); ay = fmaf(v0.y, n0, ay);
        ax = fmaf(v1.x, n1, ax); ay = fmaf(v1.y, n1, ay);
    }
    if (j < je) {
        int s0 = csrc[j];
        float n0 = cnorm[j];
        if (act) {
            float2 v0 = __half22float2(((const __half2*)(hx + (size_t)s0 * NH1))[lane]);
            ax = fmaf(v0.x, n0, ax); ay = fmaf(v0.y, n0, ay);
        }
    }
    if (act) {
        float2 bb = ((const float2*)b1)[lane];
        float2 o;
        o.x = fmaxf(ax + bb.x, 0.f);
        o.y = fmaxf(ay + bb.y, 0.f);
        *(float2*)&h[(size_t)wid * NH1 + 2 * lane] = o;
    }
}

// ---------------- GEMM2: h2 = h @ W2 (N x 100 @ 100 x 16), fp16 out ---------
__global__ __launch_bounds__(256) void k_gemm2(const float* __restrict__ h,
                                               const float* __restrict__ W2,
                                               __half* __restrict__ h2, int n) {
    __shared__ float wt[NH2 * NH1];  // transposed [col][k]
    for (int i = threadIdx.x; i < NH1 * NH2; i += 256) {
        int k = i / NH2, c = i % NH2;
        wt[c * NH1 + k] = W2[i];
    }
    __syncthreads();
    int idx = blockIdx.x * 256 + threadIdx.x;
    if (idx >= n * NH2) return;
    int row = idx >> 4, col = idx & 15;
    const float* hr = h + (size_t)row * NH1;
    const float* wr = wt + col * NH1;
    float acc = 0.f;
#pragma unroll
    for (int k = 0; k < NH1; k += 4) {
        float4 hv = *(const float4*)&hr[k];
        float4 wv = *(const float4*)&wr[k];
        acc = fmaf(hv.x, wv.x, acc);
        acc = fmaf(hv.y, wv.y, acc);
        acc = fmaf(hv.z, wv.z, acc);
        acc = fmaf(hv.w, wv.w, acc);
    }
    h2[idx] = __float2half(acc);
}

// ------- Agg layer2 + bias + relu + row-normalize (8 lanes/node, half2) -----
__global__ __launch_bounds__(256) void k_agg2(const __half* __restrict__ h2,
                                              const int* __restrict__ off,
                                              const int* __restrict__ csrc,
                                              const float* __restrict__ cnorm,
                                              const float* __restrict__ dis,
                                              const float* __restrict__ b2,
                                              __half* __restrict__ emb, int n) {
    int idx = blockIdx.x * 256 + threadIdx.x;
    int node = idx >> 3, p = idx & 7;
    if (node >= n) return;
    float dn = dis[node];
    float sn = dn * dn;
    float2 v = __half22float2(((const __half2*)(h2 + (size_t)node * NH2))[p]);
    float ax = v.x * sn, ay = v.y * sn;
    int jb = off[node], je = off[node + 1];
    int j = jb;
    for (; j + 2 <= je; j += 2) {
        int s0 = csrc[j], s1 = csrc[j + 1];
        float n0 = cnorm[j], n1 = cnorm[j + 1];
        float2 v0 = __half22float2(((const __half2*)(h2 + (size_t)s0 * NH2))[p]);
        float2 v1 = __half22float2(((const __half2*)(h2 + (size_t)s1 * NH2))[p]);
        ax = fmaf(v0.x, n0, ax); ay = fmaf(v0.y, n0, ay);
        ax = fmaf(v1.x, n1, ax); ay = fmaf(v1.y, n1, ay);
    }
    if (j < je) {
        float n0 = cnorm[j];
        float2 v0 = __half22float2(((const __half2*)(h2 + (size_t)csrc[j] * NH2))[p]);
        ax = fmaf(v0.x, n0, ax); ay = fmaf(v0.y, n0, ay);
    }
    float2 bb = ((const float2*)b2)[p];
    float vx = fmaxf(ax + bb.x, 0.f);
    float vy = fmaxf(ay + bb.y, 0.f);
    float ss = vx * vx + vy * vy;
    ss += __shfl_xor(ss, 1);
    ss += __shfl_xor(ss, 2);
    ss += __shfl_xor(ss, 4);
    float nrm = sqrtf(ss);
    float scale = nrm > 1.f ? 1.f / (nrm + 1e-7f) : 1.f;
    ((__half2*)emb)[(size_t)node * 8 + p] = __floats2half2_rn(vx * scale, vy * scale);
}

// ---------------- Decoder: thread per edge ----------------
__global__ __launch_bounds__(256) void k_dec(const __half* __restrict__ emb,
                                             const int* __restrict__ te,
                                             const float* __restrict__ PI,
                                             const float* __restrict__ ey,
                                             const float* __restrict__ Wl1,
                                             const float* __restrict__ bl1,
                                             const float* __restrict__ Wl,
                                             const float* __restrict__ bl,
                                             float* __restrict__ out, int ne) {
    int e = blockIdx.x * 256 + threadIdx.x;
    if (e >= ne) return;
    int a = te[2 * e], b = te[2 * e + 1];
    float feat[NFEAT];
    union { float4 f; __half2 h[4]; } ua0, ua1, ub0, ub1;
    ua0.f = ((const float4*)(emb + (size_t)a * NH2))[0];
    ua1.f = ((const float4*)(emb + (size_t)a * NH2))[1];
    ub0.f = ((const float4*)(emb + (size_t)b * NH2))[0];
    ub1.f = ((const float4*)(emb + (size_t)b * NH2))[1];
#pragma unroll
    for (int q = 0; q < 4; ++q) {
        float2 va = __half22float2(ua0.h[q]);
        float2 vb = __half22float2(ub0.h[q]);
        float dx = va.x - vb.x, dy = va.y - vb.y;
        feat[2 * q] = dx * dx; feat[2 * q + 1] = dy * dy;
        float2 vc = __half22float2(ua1.h[q]);
        float2 vd = __half22float2(ub1.h[q]);
        float dz = vc.x - vd.x, dw = vc.y - vd.y;
        feat[8 + 2 * q] = dz * dz; feat[8 + 2 * q + 1] = dw * dw;
    }
    const float* pi = PI + (size_t)e * ND2;
#pragma unroll
    for (int q = 0; q < ND2; ++q) feat[NH2 + q] = pi[q];
    float s = 0.f;
    for (int j = 0; j < ND2; ++j) {
        float acc = bl1[j];
#pragma unroll
        for (int k = 0; k < NFEAT; ++k) acc = fmaf(feat[k], Wl1[k * ND2 + j], acc);
        acc = acc > 0.f ? acc : 0.2f * acc;  // leaky_relu slope 0.2
        s = fmaf(acc, Wl[j], s);
    }
    s += bl[0];
    s = fabsf(s);
    s = fminf(s, 40.0f);
    out[e] = 1.0f / (expf(s - 2.0f) + 1.0f);
    out[ne + e] = ey[e];
}

static inline int cdiv(int a, int b) { return (a + b - 1) / b; }

extern "C" void kernel_launch(void* const* d_in, const int* in_sizes, int n_in,
                              void* d_out, int out_size, void* d_ws, size_t ws_size,
                              hipStream_t stream) {
    const float* x   = (const float*)d_in[0];
    const int*   ei  = (const int*)d_in[1];
    const int*   te  = (const int*)d_in[2];
    const float* PI  = (const float*)d_in[3];
    const float* ey  = (const float*)d_in[4];
    const float* W1  = (const float*)d_in[5];
    const float* b1  = (const float*)d_in[6];
    const float* W2  = (const float*)d_in[7];
    const float* b2  = (const float*)d_in[8];
    const float* Wl1 = (const float*)d_in[9];
    const float* bl1 = (const float*)d_in[10];
    const float* Wl  = (const float*)d_in[11];
    const float* bl  = (const float*)d_in[12];
    float* out = (float*)d_out;

    const int n  = in_sizes[0] / NN_F;   // 50000
    const int E  = in_sizes[1] / 2;      // 800000
    const int ne = in_sizes[4];          // 200000

    // workspace carve-up
    char* ws = (char*)d_ws;
    size_t o = 0;
    auto carve = [&](size_t bytes) -> void* {
        void* p = ws + o;
        o = (o + bytes + 255) & ~(size_t)255;
        return p;
    };
    int*    cnt      = (int*)carve((size_t)n * 4);
    float*  dis      = (float*)carve((size_t)n * 4);
    int*    off      = (int*)carve((size_t)(n + 1) * 4);
    int*    cur      = (int*)carve((size_t)n * 4);
    int*    partials = (int*)carve(256 * 4);
    int*    csrc     = (int*)carve((size_t)E * 4);
    float*  cnorm    = (float*)carve((size_t)E * 4);
    __half* hx       = (__half*)carve((size_t)n * NH1 * 2);
    float*  h        = (float*)carve((size_t)n * NH1 * 4);
    __half* h2       = (__half*)carve((size_t)n * NH2 * 2);
    __half* emb      = (__half*)carve((size_t)n * NH2 * 2);

    const int NB = cdiv(n, 256);  // 196

    hipMemsetAsync(cnt, 0, (size_t)n * 4, stream);
    hipMemsetAsync(cur, 0, (size_t)n * 4, stream);

    k_count<<<cdiv(E, 256), 256, 0, stream>>>(ei, cnt, E);
    k_dis<<<NB, 256, 0, stream>>>(cnt, dis, n);
    k_scan1<<<NB, 256, 0, stream>>>(cnt, off, partials, n);
    k_scan2<<<1, 256, 0, stream>>>(partials, NB);
    k_scan3<<<NB, 256, 0, stream>>>(off, partials, n, E);
    k_fill<<<cdiv(E, 256), 256, 0, stream>>>(ei, off, cur, dis, csrc, cnorm, E);

    k_gemm1<<<cdiv((n / 2) * 25, 256), 256, 0, stream>>>(x, W1, hx, n / 2);
    k_agg1<<<cdiv(n * 64, 256), 256, 0, stream>>>(hx, off, csrc, cnorm, dis, b1, h, n);
    k_gemm2<<<cdiv(n * NH2, 256), 256, 0, stream>>>(h, W2, h2, n);
    k_agg2<<<cdiv(n * 8, 256), 256, 0, stream>>>(h2, off, csrc, cnorm, dis, b2, emb, n);
    k_dec<<<cdiv(ne, 256), 256, 0, stream>>>(emb, te, PI, ey, Wl1, bl1, Wl, bl, out, ne);
}